// Round 7
// baseline (95.605 us; speedup 1.0000x reference)
//
#include <hip/hip_runtime.h>
#include <math.h>

// Constants: MASS=1.0, CHARGE=0.5, ALPHA=0.1, BETA=0.05, ETA=(+1,-1,-1,-1)
// Round 13: single fused kernel with per-block LDS compaction of the slow
// tier. Structure replaces rounds 8-12's {global list + memset + second
// kernel} with an in-block mop-up:
//   - Tier 1 (~99% lanes): all-f32 model + Sherman-Morrison, safe when
//     |det| > rowmax^4/1024 => kappa <= 1024 (proven via lambda_min >=
//     |det|/sigma^3, sigma <= rowmax).
//   - Unsafe lanes push their index to an LDS list (~2.6/block).
//   - After __syncthreads(), threads 0..nd-1 (usually one wave) run the f64
//     tier for the listed lanes: f64 model + SIX_RCOND criterion -> f64 SM,
//     else register-resident Jacobi + truncated pinv (rcond =
//     10*max(M,N)*eps_f32 = jnp.linalg.pinv default).
// Why: every block's mop-up runs concurrently across CUs, so the whole tail
// costs ~one Jacobi chain (~5us) of makespan instead of a serialized second
// phase; and the f64 model runs on ~23% of wave-slots instead of 47% of
// waves (R4/R6 inline tier-2). No workspace, no memset, no global atomics.
// Routing semantics identical to the passing R4/R6 kernels.

#define SIX_RCOND 2.86102294921875e-5   // 6 * 4.76837158203125e-6
#define RCOND     4.76837158203125e-6

// ------------------------------ f32 helpers --------------------------------
__device__ __forceinline__ float rcp_nr(float x) {
    float r = __builtin_amdgcn_rcpf(x);
    r = r * (2.0f - x * r);              // one Newton step -> ~1 ulp
    return r;
}

// ------------------------------ f64 helpers --------------------------------
__device__ __forceinline__ void fast_tanh4(const double t[4], double th[4])
{
    const double LOG2E = 1.4426950408889634074;
    const double LN2HI = 6.93147180369123816490e-01;
    const double LN2LO = 1.90821492927058770002e-10;
    double e[4], opp[4];
    #pragma unroll
    for (int j = 0; j < 4; ++j) {
        double a  = fabs(t[j]);
        double z  = -2.0 * a;
        double zc = fmax(z, -64.0);
        double nf = rint(zc * LOG2E);
        double r  = fma(-nf, LN2HI, zc);
        r = fma(-nf, LN2LO, r);
        double p = 2.75573192239858906526e-07;
        p = fma(p, r, 2.75573192239858925110e-06);
        p = fma(p, r, 2.48015873015873015873e-05);
        p = fma(p, r, 1.98412698412698412698e-04);
        p = fma(p, r, 1.38888888888888888889e-03);
        p = fma(p, r, 8.33333333333333333333e-03);
        p = fma(p, r, 4.16666666666666666667e-02);
        p = fma(p, r, 1.66666666666666666667e-01);
        p = fma(p, r, 0.5);
        p = fma(p, r, 1.0);
        p = fma(p, r, 1.0);
        int n = (int)nf;
        double twon = __longlong_as_double(((long long)(1023 + n)) << 52);
        double ez = p * twon;
        ez = (z <= -40.0) ? 0.0 : ez;
        e[j]   = ez;
        opp[j] = 1.0 + ez;
    }
    double p01 = opp[0] * opp[1], p23 = opp[2] * opp[3];
    double rp  = 1.0 / (p01 * p23);
    double inv[4] = { opp[1] * p23 * rp, opp[0] * p23 * rp,
                      p01 * opp[3] * rp, p01 * opp[2] * rp };
    #pragma unroll
    for (int j = 0; j < 4; ++j)
        th[j] = copysign((1.0 - e[j]) * inv[j], t[j]);
}

__device__ __forceinline__ void model_terms_f64(
    const double* sW, const double* sV,
    const double x[4], const double u[4],
    double A[4], double f[4], double d[4])
{
    const double eta[4] = {1.0, -1.0, -1.0, -1.0};
    const double CHG = 0.5, ALPHA = 0.1, BETA = 0.05;
    double t[4], s[4];
    #pragma unroll
    for (int j = 0; j < 4; ++j) {
        double tj = 0.0, sj = 0.0;
        #pragma unroll
        for (int k = 0; k < 4; ++k) {
            tj = fma(sW[j*4+k], x[k], tj);
            sj = fma(sV[j*4+k], x[k], sj);
        }
        t[j] = tj; s[j] = sj;
    }
    double th[4];
    fast_tanh4(t, th);
    double G[4][4];
    #pragma unroll
    for (int j = 0; j < 4; ++j) {
        A[j] = th[j] + s[j];
        double dth = 1.0 - th[j] * th[j];
        #pragma unroll
        for (int k = 0; k < 4; ++k) G[j][k] = fma(dth, sW[j*4+k], sV[j*4+k]);
    }
    double S = 0.0;
    #pragma unroll
    for (int k = 0; k < 4; ++k) S += u[k] * A[k];
    double P[4], R[4], Q[4];
    #pragma unroll
    for (int j = 0; j < 4; ++j) {
        double p = 0.0, r = 0.0, q = 0.0;
        #pragma unroll
        for (int k = 0; k < 4; ++k) {
            p += G[k][j] * u[k];
            r += G[j][k] * u[k];
            q += G[k][j] * (CHG * eta[k]) * u[k];
        }
        P[j] = p; R[j] = r; Q[j] = q;
    }
    double T = 0.0;
    #pragma unroll
    for (int j = 0; j < 4; ++j) T += u[j] * R[j];
    #pragma unroll
    for (int j = 0; j < 4; ++j) {
        f[j] = -2.0 * ALPHA * x[j] * u[j] * u[j]
             + Q[j]
             + 2.0 * BETA * S * P[j]
             - (CHG * eta[j] + 2.0 * BETA * S) * R[j]
             - 2.0 * BETA * A[j] * T;
        d[j] = eta[j] + 2.0 * ALPHA * x[j] * x[j];
    }
}

__device__ __forceinline__ void sm_solve_f64(
    const double d[4], const double A[4], const double f[4], double acc[4])
{
    const double C2 = 0.1;
    double b[4], fd[4], den = 1.0, w = 0.0;
    #pragma unroll
    for (int j = 0; j < 4; ++j) {
        double inv = 1.0 / d[j];
        b[j]  = A[j] * inv;
        fd[j] = f[j] * inv;
        den  += C2 * A[j] * b[j];
        w    += b[j] * f[j];
    }
    double scale = C2 * w / den;
    #pragma unroll
    for (int j = 0; j < 4; ++j) acc[j] = fd[j] - b[j] * scale;
}

// f64 safety criterion: |det| > SIX_RCOND * min(F2, rowmax^2)^2 && min|d|>1e-3
__device__ __forceinline__ bool criterion_f64(
    const double d[4], const double A[4])
{
    const double C2 = 0.1;
    double mind = 1e300;
    #pragma unroll
    for (int j = 0; j < 4; ++j) {
        double a = fabs(d[j]);
        mind = (a < mind) ? a : mind;
    }
    double p01 = d[0] * d[1], p23 = d[2] * d[3];
    double det = p01 * p23
        + C2 * (A[0]*A[0]*(d[1]*p23) + A[1]*A[1]*(d[0]*p23) +
                A[2]*A[2]*(p01*d[3]) + A[3]*A[3]*(p01*d[2]));
    double sumA2 = 0.0, sumA4 = 0.0, F2 = 0.0;
    #pragma unroll
    for (int j = 0; j < 4; ++j) {
        double Aj2 = A[j] * A[j];
        sumA2 += Aj2; sumA4 += Aj2 * Aj2;
        double Jjj = d[j] + C2 * Aj2;
        F2 += Jjj * Jjj;
    }
    F2 += C2 * C2 * (sumA2 * sumA2 - sumA4);
    double rowmax = 0.0;
    #pragma unroll
    for (int r = 0; r < 4; ++r) {
        double rs = 0.0;
        #pragma unroll
        for (int c = 0; c < 4; ++c) {
            double Jrc = C2 * A[r] * A[c] + ((r == c) ? d[r] : 0.0);
            rs += fabs(Jrc);
        }
        rowmax = (rs > rowmax) ? rs : rowmax;
    }
    double sig_hi2 = rowmax * rowmax;
    sig_hi2 = (F2 < sig_hi2) ? F2 : sig_hi2;
    return (fabs(det) > SIX_RCOND * sig_hi2 * sig_hi2) && (mind > 1e-3);
}

// Branch-free 4x4 symmetric Jacobi + truncated pinv, register-resident.
__device__ __forceinline__ void jacobi_pinv_reg(
    const double d[4], const double A[4], const double f[4], double acc[4])
{
    const double C2 = 0.1;
    double M[4][4], Vm[4][4];
    #pragma unroll
    for (int r = 0; r < 4; ++r) {
        #pragma unroll
        for (int c = 0; c < 4; ++c) {
            M[r][c] = C2 * A[r] * A[c];
            Vm[r][c] = (r == c) ? 1.0 : 0.0;
        }
        M[r][r] += d[r];
    }
    for (int sweep = 0; sweep < 8; ++sweep) {
        #pragma unroll
        for (int p = 0; p < 3; ++p) {
            #pragma unroll
            for (int q2 = p + 1; q2 < 4; ++q2) {
                double apq = M[p][q2];
                bool active = fabs(apq) > 1e-280;
                double div = active ? (2.0 * apq) : 1.0;
                double tau = (M[q2][q2] - M[p][p]) / div;
                double tt = ((tau >= 0.0) ? 1.0 : -1.0) /
                            (fabs(tau) + sqrt(1.0 + tau * tau));
                double c = 1.0 / sqrt(1.0 + tt * tt);
                double s = tt * c;
                c = active ? c : 1.0;     // identity rotation if apq ~ 0
                s = active ? s : 0.0;
                #pragma unroll
                for (int k = 0; k < 4; ++k) {
                    double mkp = M[k][p], mkq = M[k][q2];
                    M[k][p]  = c * mkp - s * mkq;
                    M[k][q2] = s * mkp + c * mkq;
                }
                #pragma unroll
                for (int k = 0; k < 4; ++k) {
                    double mpk = M[p][k], mqk = M[q2][k];
                    M[p][k]  = c * mpk - s * mqk;
                    M[q2][k] = s * mpk + c * mqk;
                }
                #pragma unroll
                for (int k = 0; k < 4; ++k) {
                    double vkp = Vm[k][p], vkq = Vm[k][q2];
                    Vm[k][p]  = c * vkp - s * vkq;
                    Vm[k][q2] = s * vkp + c * vkq;
                }
            }
        }
    }
    double lam[4], sigmax = 0.0;
    #pragma unroll
    for (int k = 0; k < 4; ++k) {
        lam[k] = M[k][k];
        double a = fabs(lam[k]);
        sigmax = (a > sigmax) ? a : sigmax;
    }
    double cutoff = RCOND * sigmax;
    #pragma unroll
    for (int j = 0; j < 4; ++j) acc[j] = 0.0;
    #pragma unroll
    for (int e = 0; e < 4; ++e) {
        double coef = 0.0;
        #pragma unroll
        for (int k = 0; k < 4; ++k) coef += Vm[k][e] * f[k];
        coef /= lam[e];
        coef = (fabs(lam[e]) > cutoff) ? coef : 0.0;   // truncate small modes
        #pragma unroll
        for (int j = 0; j < 4; ++j) acc[j] += coef * Vm[j][e];
    }
}

// ---------------- Fused kernel: f32 fast path + in-block f64 mop-up --------
__global__ __launch_bounds__(256, 2) void fused_kernel(
    const float* __restrict__ y, const float* __restrict__ W,
    const float* __restrict__ V, float* __restrict__ out, int B)
{
    __shared__ float  sW[16],  sV[16];
    __shared__ double sWd[16], sVd[16];
    __shared__ int sList[256];
    __shared__ int sCount;

    if (threadIdx.x == 0) sCount = 0;
    if (threadIdx.x < 16) {
        float w = W[threadIdx.x];
        sW[threadIdx.x]  = w;
        sWd[threadIdx.x] = (double)w;
    } else if (threadIdx.x < 32) {
        float v = V[threadIdx.x - 16];
        sV[threadIdx.x - 16]  = v;
        sVd[threadIdx.x - 16] = (double)v;
    }
    __syncthreads();

    int i = blockIdx.x * blockDim.x + threadIdx.x;
    const float4* y4 = (const float4*)y;

    if (i < B) {
        float4 xv = y4[2 * i];
        float4 uv = y4[2 * i + 1];
        float x[4] = {xv.x, xv.y, xv.z, xv.w};
        float u[4] = {uv.x, uv.y, uv.z, uv.w};

        const float eta[4] = {1.0f, -1.0f, -1.0f, -1.0f};
        const float CHG = 0.5f, ALPHA = 0.1f, BETA = 0.05f, C2 = 0.1f;
        const float NEG2LOG2E = -2.8853900817779268f;   // -2*log2(e)

        float t[4], sv[4];
        #pragma unroll
        for (int j = 0; j < 4; ++j) {
            float tj = 0.0f, sj = 0.0f;
            #pragma unroll
            for (int k = 0; k < 4; ++k) {
                tj = fmaf(sW[j*4+k], x[k], tj);
                sj = fmaf(sV[j*4+k], x[k], sj);
            }
            t[j] = tj; sv[j] = sj;
        }
        float A[4], dth[4];
        #pragma unroll
        for (int j = 0; j < 4; ++j) {
            float a  = fabsf(t[j]);
            float e  = __builtin_amdgcn_exp2f(a * NEG2LOG2E); // underflow->0 -> th=1
            float th = copysignf((1.0f - e) * rcp_nr(1.0f + e), t[j]);
            A[j]   = th + sv[j];
            dth[j] = 1.0f - th * th;
        }
        float G[4][4];
        #pragma unroll
        for (int j = 0; j < 4; ++j)
            #pragma unroll
            for (int k = 0; k < 4; ++k)
                G[j][k] = fmaf(dth[j], sW[j*4+k], sV[j*4+k]);

        float S = 0.0f;
        #pragma unroll
        for (int k = 0; k < 4; ++k) S = fmaf(u[k], A[k], S);
        float P[4], R[4], Q[4];
        #pragma unroll
        for (int j = 0; j < 4; ++j) {
            float p = 0.0f, r = 0.0f, q = 0.0f;
            #pragma unroll
            for (int k = 0; k < 4; ++k) {
                p = fmaf(G[k][j], u[k], p);
                r = fmaf(G[j][k], u[k], r);
                q = fmaf(G[k][j] * (CHG * eta[k]), u[k], q);
            }
            P[j] = p; R[j] = r; Q[j] = q;
        }
        float T = 0.0f;
        #pragma unroll
        for (int j = 0; j < 4; ++j) T = fmaf(u[j], R[j], T);
        float f[4], d[4];
        #pragma unroll
        for (int j = 0; j < 4; ++j) {
            f[j] = -2.0f * ALPHA * x[j] * u[j] * u[j]
                 + Q[j]
                 + 2.0f * BETA * S * P[j]
                 - (CHG * eta[j] + 2.0f * BETA * S) * R[j]
                 - 2.0f * BETA * A[j] * T;
            d[j] = eta[j] + 2.0f * ALPHA * x[j] * x[j];
        }

        // --- tier-1 gate: |det| > rowmax^4 / 1024  =>  kappa <= 1024 ---
        float mind = fminf(fminf(fabsf(d[0]), fabsf(d[1])),
                           fminf(fabsf(d[2]), fabsf(d[3])));
        float p01 = d[0] * d[1], p23 = d[2] * d[3];
        float prod = p01 * p23;
        float det = prod
            + C2 * (A[0]*A[0]*(d[1]*p23) + A[1]*A[1]*(d[0]*p23) +
                    A[2]*A[2]*(p01*d[3]) + A[3]*A[3]*(p01*d[2]));
        float rowmax = 0.0f;
        #pragma unroll
        for (int r = 0; r < 4; ++r) {
            float rs = 0.0f;
            #pragma unroll
            for (int c = 0; c < 4; ++c) {
                float Jrc = C2 * A[r] * A[c] + ((r == c) ? d[r] : 0.0f);
                rs += fabsf(Jrc);
            }
            rowmax = fmaxf(rs, rowmax);
        }
        float sig2 = rowmax * rowmax;
        bool safe = (fabsf(det) > sig2 * sig2 * (1.0f / 1024.0f)) && (mind > 1e-3f);

        if (safe) {
            float invprod = rcp_nr(prod);
            float invd[4] = { d[1] * p23 * invprod, d[0] * p23 * invprod,
                              p01 * d[3] * invprod, p01 * d[2] * invprod };
            float b[4], fd[4], den = 1.0f, w = 0.0f;
            #pragma unroll
            for (int j = 0; j < 4; ++j) {
                b[j]  = A[j] * invd[j];
                fd[j] = f[j] * invd[j];
                den   = fmaf(C2 * A[j], b[j], den);
                w     = fmaf(b[j], f[j], w);
            }
            float scale = (C2 * w) * rcp_nr(den);
            float4 res;
            res.x = fd[0] - b[0] * scale; res.y = fd[1] - b[1] * scale;
            res.z = fd[2] - b[2] * scale; res.w = fd[3] - b[3] * scale;
            ((float4*)out)[i] = res;
        } else {
            int k = atomicAdd(&sCount, 1);     // LDS atomic, cheap
            sList[k] = i;
        }
    }
    __syncthreads();

    // --- in-block f64 mop-up: threads 0..nd-1 handle the deferred lanes ---
    int nd = sCount;
    for (int base = 0; base < nd; base += blockDim.x) {
        int idx = base + (int)threadIdx.x;
        if (idx < nd) {
            int ii = sList[idx];
            float4 xv = y4[2 * ii];
            float4 uv = y4[2 * ii + 1];
            double x[4] = {xv.x, xv.y, xv.z, xv.w};
            double u[4] = {uv.x, uv.y, uv.z, uv.w};
            double A[4], f[4], d[4];
            model_terms_f64(sWd, sVd, x, u, A, f, d);

            double acc[4];
            if (criterion_f64(d, A)) sm_solve_f64(d, A, f, acc);
            else                     jacobi_pinv_reg(d, A, f, acc);

            float4 res;
            res.x = (float)acc[0]; res.y = (float)acc[1];
            res.z = (float)acc[2]; res.w = (float)acc[3];
            ((float4*)out)[ii] = res;
        }
    }
}

extern "C" void kernel_launch(void* const* d_in, const int* in_sizes, int n_in,
                              void* d_out, int out_size, void* d_ws, size_t ws_size,
                              hipStream_t stream) {
    const float* y = (const float*)d_in[0];
    const float* W = (const float*)d_in[1];
    const float* V = (const float*)d_in[2];
    float* out = (float*)d_out;
    int B = in_sizes[0] / 8;

    int block = 256;
    int grid = (B + block - 1) / block;
    fused_kernel<<<grid, block, 0, stream>>>(y, W, V, out, B);
}

// Round 8
// 85.683 us; speedup vs baseline: 1.1158x; 1.1158x over previous
//
#include <hip/hip_runtime.h>
#include <math.h>

// Constants: MASS=1.0, CHARGE=0.5, ALPHA=0.1, BETA=0.05, ETA=(+1,-1,-1,-1)
// Round 14: split the mop-up. R7's fused kernel proved (VGPR=100, occ 3.1%,
// 62us) that inlining the Jacobi spills and serializes the whole kernel.
//   - fused_kernel: tier-1 f32 SM (kappa<=1024 gate) + per-block LDS
//     compaction; mop-up threads run f64 model + SIX_RCOND criterion + f64
//     SM ONLY (no Jacobi -> no spill). Truly-unsafe lanes (~500 total)
//     append to a global list (few atomics/block).
//   - slow_kernel: register-resident Jacobi + truncated pinv (rcond =
//     10*max(M,N)*eps_f32 = jnp.linalg.pinv default) at 64-thread blocks,
//     __launch_bounds__(64,1) -> VGPR budget up to 512 for M+Vm.
// Routing semantics identical to R4/R6/R7 (same gates, same lanes).

#define SIX_RCOND 2.86102294921875e-5   // 6 * 4.76837158203125e-6
#define RCOND     4.76837158203125e-6

// ------------------------------ f32 helpers --------------------------------
__device__ __forceinline__ float rcp_nr(float x) {
    float r = __builtin_amdgcn_rcpf(x);
    r = r * (2.0f - x * r);              // one Newton step -> ~1 ulp
    return r;
}

// ------------------------------ f64 helpers --------------------------------
__device__ __forceinline__ void fast_tanh4(const double t[4], double th[4])
{
    const double LOG2E = 1.4426950408889634074;
    const double LN2HI = 6.93147180369123816490e-01;
    const double LN2LO = 1.90821492927058770002e-10;
    double e[4], opp[4];
    #pragma unroll
    for (int j = 0; j < 4; ++j) {
        double a  = fabs(t[j]);
        double z  = -2.0 * a;
        double zc = fmax(z, -64.0);
        double nf = rint(zc * LOG2E);
        double r  = fma(-nf, LN2HI, zc);
        r = fma(-nf, LN2LO, r);
        double p = 2.75573192239858906526e-07;
        p = fma(p, r, 2.75573192239858925110e-06);
        p = fma(p, r, 2.48015873015873015873e-05);
        p = fma(p, r, 1.98412698412698412698e-04);
        p = fma(p, r, 1.38888888888888888889e-03);
        p = fma(p, r, 8.33333333333333333333e-03);
        p = fma(p, r, 4.16666666666666666667e-02);
        p = fma(p, r, 1.66666666666666666667e-01);
        p = fma(p, r, 0.5);
        p = fma(p, r, 1.0);
        p = fma(p, r, 1.0);
        int n = (int)nf;
        double twon = __longlong_as_double(((long long)(1023 + n)) << 52);
        double ez = p * twon;
        ez = (z <= -40.0) ? 0.0 : ez;
        e[j]   = ez;
        opp[j] = 1.0 + ez;
    }
    double p01 = opp[0] * opp[1], p23 = opp[2] * opp[3];
    double rp  = 1.0 / (p01 * p23);
    double inv[4] = { opp[1] * p23 * rp, opp[0] * p23 * rp,
                      p01 * opp[3] * rp, p01 * opp[2] * rp };
    #pragma unroll
    for (int j = 0; j < 4; ++j)
        th[j] = copysign((1.0 - e[j]) * inv[j], t[j]);
}

__device__ __forceinline__ void model_terms_f64(
    const double* sW, const double* sV,
    const double x[4], const double u[4],
    double A[4], double f[4], double d[4])
{
    const double eta[4] = {1.0, -1.0, -1.0, -1.0};
    const double CHG = 0.5, ALPHA = 0.1, BETA = 0.05;
    double t[4], s[4];
    #pragma unroll
    for (int j = 0; j < 4; ++j) {
        double tj = 0.0, sj = 0.0;
        #pragma unroll
        for (int k = 0; k < 4; ++k) {
            tj = fma(sW[j*4+k], x[k], tj);
            sj = fma(sV[j*4+k], x[k], sj);
        }
        t[j] = tj; s[j] = sj;
    }
    double th[4];
    fast_tanh4(t, th);
    double G[4][4];
    #pragma unroll
    for (int j = 0; j < 4; ++j) {
        A[j] = th[j] + s[j];
        double dth = 1.0 - th[j] * th[j];
        #pragma unroll
        for (int k = 0; k < 4; ++k) G[j][k] = fma(dth, sW[j*4+k], sV[j*4+k]);
    }
    double S = 0.0;
    #pragma unroll
    for (int k = 0; k < 4; ++k) S += u[k] * A[k];
    double P[4], R[4], Q[4];
    #pragma unroll
    for (int j = 0; j < 4; ++j) {
        double p = 0.0, r = 0.0, q = 0.0;
        #pragma unroll
        for (int k = 0; k < 4; ++k) {
            p += G[k][j] * u[k];
            r += G[j][k] * u[k];
            q += G[k][j] * (CHG * eta[k]) * u[k];
        }
        P[j] = p; R[j] = r; Q[j] = q;
    }
    double T = 0.0;
    #pragma unroll
    for (int j = 0; j < 4; ++j) T += u[j] * R[j];
    #pragma unroll
    for (int j = 0; j < 4; ++j) {
        f[j] = -2.0 * ALPHA * x[j] * u[j] * u[j]
             + Q[j]
             + 2.0 * BETA * S * P[j]
             - (CHG * eta[j] + 2.0 * BETA * S) * R[j]
             - 2.0 * BETA * A[j] * T;
        d[j] = eta[j] + 2.0 * ALPHA * x[j] * x[j];
    }
}

__device__ __forceinline__ void sm_solve_f64(
    const double d[4], const double A[4], const double f[4], double acc[4])
{
    const double C2 = 0.1;
    double b[4], fd[4], den = 1.0, w = 0.0;
    #pragma unroll
    for (int j = 0; j < 4; ++j) {
        double inv = 1.0 / d[j];
        b[j]  = A[j] * inv;
        fd[j] = f[j] * inv;
        den  += C2 * A[j] * b[j];
        w    += b[j] * f[j];
    }
    double scale = C2 * w / den;
    #pragma unroll
    for (int j = 0; j < 4; ++j) acc[j] = fd[j] - b[j] * scale;
}

// f64 safety criterion: |det| > SIX_RCOND * min(F2, rowmax^2)^2 && min|d|>1e-3
__device__ __forceinline__ bool criterion_f64(
    const double d[4], const double A[4])
{
    const double C2 = 0.1;
    double mind = 1e300;
    #pragma unroll
    for (int j = 0; j < 4; ++j) {
        double a = fabs(d[j]);
        mind = (a < mind) ? a : mind;
    }
    double p01 = d[0] * d[1], p23 = d[2] * d[3];
    double det = p01 * p23
        + C2 * (A[0]*A[0]*(d[1]*p23) + A[1]*A[1]*(d[0]*p23) +
                A[2]*A[2]*(p01*d[3]) + A[3]*A[3]*(p01*d[2]));
    double sumA2 = 0.0, sumA4 = 0.0, F2 = 0.0;
    #pragma unroll
    for (int j = 0; j < 4; ++j) {
        double Aj2 = A[j] * A[j];
        sumA2 += Aj2; sumA4 += Aj2 * Aj2;
        double Jjj = d[j] + C2 * Aj2;
        F2 += Jjj * Jjj;
    }
    F2 += C2 * C2 * (sumA2 * sumA2 - sumA4);
    double rowmax = 0.0;
    #pragma unroll
    for (int r = 0; r < 4; ++r) {
        double rs = 0.0;
        #pragma unroll
        for (int c = 0; c < 4; ++c) {
            double Jrc = C2 * A[r] * A[c] + ((r == c) ? d[r] : 0.0);
            rs += fabs(Jrc);
        }
        rowmax = (rs > rowmax) ? rs : rowmax;
    }
    double sig_hi2 = rowmax * rowmax;
    sig_hi2 = (F2 < sig_hi2) ? F2 : sig_hi2;
    return (fabs(det) > SIX_RCOND * sig_hi2 * sig_hi2) && (mind > 1e-3);
}

// Branch-free 4x4 symmetric Jacobi + truncated pinv, register-resident.
__device__ __forceinline__ void jacobi_pinv_reg(
    const double d[4], const double A[4], const double f[4], double acc[4])
{
    const double C2 = 0.1;
    double M[4][4], Vm[4][4];
    #pragma unroll
    for (int r = 0; r < 4; ++r) {
        #pragma unroll
        for (int c = 0; c < 4; ++c) {
            M[r][c] = C2 * A[r] * A[c];
            Vm[r][c] = (r == c) ? 1.0 : 0.0;
        }
        M[r][r] += d[r];
    }
    for (int sweep = 0; sweep < 8; ++sweep) {
        #pragma unroll
        for (int p = 0; p < 3; ++p) {
            #pragma unroll
            for (int q2 = p + 1; q2 < 4; ++q2) {
                double apq = M[p][q2];
                bool active = fabs(apq) > 1e-280;
                double div = active ? (2.0 * apq) : 1.0;
                double tau = (M[q2][q2] - M[p][p]) / div;
                double tt = ((tau >= 0.0) ? 1.0 : -1.0) /
                            (fabs(tau) + sqrt(1.0 + tau * tau));
                double c = 1.0 / sqrt(1.0 + tt * tt);
                double s = tt * c;
                c = active ? c : 1.0;     // identity rotation if apq ~ 0
                s = active ? s : 0.0;
                #pragma unroll
                for (int k = 0; k < 4; ++k) {
                    double mkp = M[k][p], mkq = M[k][q2];
                    M[k][p]  = c * mkp - s * mkq;
                    M[k][q2] = s * mkp + c * mkq;
                }
                #pragma unroll
                for (int k = 0; k < 4; ++k) {
                    double mpk = M[p][k], mqk = M[q2][k];
                    M[p][k]  = c * mpk - s * mqk;
                    M[q2][k] = s * mpk + c * mqk;
                }
                #pragma unroll
                for (int k = 0; k < 4; ++k) {
                    double vkp = Vm[k][p], vkq = Vm[k][q2];
                    Vm[k][p]  = c * vkp - s * vkq;
                    Vm[k][q2] = s * vkp + c * vkq;
                }
            }
        }
    }
    double lam[4], sigmax = 0.0;
    #pragma unroll
    for (int k = 0; k < 4; ++k) {
        lam[k] = M[k][k];
        double a = fabs(lam[k]);
        sigmax = (a > sigmax) ? a : sigmax;
    }
    double cutoff = RCOND * sigmax;
    #pragma unroll
    for (int j = 0; j < 4; ++j) acc[j] = 0.0;
    #pragma unroll
    for (int e = 0; e < 4; ++e) {
        double coef = 0.0;
        #pragma unroll
        for (int k = 0; k < 4; ++k) coef += Vm[k][e] * f[k];
        coef /= lam[e];
        coef = (fabs(lam[e]) > cutoff) ? coef : 0.0;   // truncate small modes
        #pragma unroll
        for (int j = 0; j < 4; ++j) acc[j] += coef * Vm[j][e];
    }
}

// ------- Fused kernel: f32 tier-1 + in-block f64 model/SM mop-up -----------
// No Jacobi inside -> no spill pressure. Truly-unsafe lanes go to a global
// list for the separate slow_kernel.
__global__ __launch_bounds__(256, 2) void fused_kernel(
    const float* __restrict__ y, const float* __restrict__ W,
    const float* __restrict__ V, float* __restrict__ out,
    unsigned int* __restrict__ cnt, int* __restrict__ list,
    unsigned int cap, int B)
{
    __shared__ float  sW[16],  sV[16];
    __shared__ double sWd[16], sVd[16];
    __shared__ int sList[256];
    __shared__ int sCount;

    if (threadIdx.x == 0) sCount = 0;
    if (threadIdx.x < 16) {
        float w = W[threadIdx.x];
        sW[threadIdx.x]  = w;
        sWd[threadIdx.x] = (double)w;
    } else if (threadIdx.x < 32) {
        float v = V[threadIdx.x - 16];
        sV[threadIdx.x - 16]  = v;
        sVd[threadIdx.x - 16] = (double)v;
    }
    __syncthreads();

    int i = blockIdx.x * blockDim.x + threadIdx.x;
    const float4* y4 = (const float4*)y;

    if (i < B) {
        float4 xv = y4[2 * i];
        float4 uv = y4[2 * i + 1];
        float x[4] = {xv.x, xv.y, xv.z, xv.w};
        float u[4] = {uv.x, uv.y, uv.z, uv.w};

        const float eta[4] = {1.0f, -1.0f, -1.0f, -1.0f};
        const float CHG = 0.5f, ALPHA = 0.1f, BETA = 0.05f, C2 = 0.1f;
        const float NEG2LOG2E = -2.8853900817779268f;   // -2*log2(e)

        float t[4], sv[4];
        #pragma unroll
        for (int j = 0; j < 4; ++j) {
            float tj = 0.0f, sj = 0.0f;
            #pragma unroll
            for (int k = 0; k < 4; ++k) {
                tj = fmaf(sW[j*4+k], x[k], tj);
                sj = fmaf(sV[j*4+k], x[k], sj);
            }
            t[j] = tj; sv[j] = sj;
        }
        float A[4], dth[4];
        #pragma unroll
        for (int j = 0; j < 4; ++j) {
            float a  = fabsf(t[j]);
            float e  = __builtin_amdgcn_exp2f(a * NEG2LOG2E); // underflow->0 -> th=1
            float th = copysignf((1.0f - e) * rcp_nr(1.0f + e), t[j]);
            A[j]   = th + sv[j];
            dth[j] = 1.0f - th * th;
        }
        float G[4][4];
        #pragma unroll
        for (int j = 0; j < 4; ++j)
            #pragma unroll
            for (int k = 0; k < 4; ++k)
                G[j][k] = fmaf(dth[j], sW[j*4+k], sV[j*4+k]);

        float S = 0.0f;
        #pragma unroll
        for (int k = 0; k < 4; ++k) S = fmaf(u[k], A[k], S);
        float P[4], R[4], Q[4];
        #pragma unroll
        for (int j = 0; j < 4; ++j) {
            float p = 0.0f, r = 0.0f, q = 0.0f;
            #pragma unroll
            for (int k = 0; k < 4; ++k) {
                p = fmaf(G[k][j], u[k], p);
                r = fmaf(G[j][k], u[k], r);
                q = fmaf(G[k][j] * (CHG * eta[k]), u[k], q);
            }
            P[j] = p; R[j] = r; Q[j] = q;
        }
        float T = 0.0f;
        #pragma unroll
        for (int j = 0; j < 4; ++j) T = fmaf(u[j], R[j], T);
        float f[4], d[4];
        #pragma unroll
        for (int j = 0; j < 4; ++j) {
            f[j] = -2.0f * ALPHA * x[j] * u[j] * u[j]
                 + Q[j]
                 + 2.0f * BETA * S * P[j]
                 - (CHG * eta[j] + 2.0f * BETA * S) * R[j]
                 - 2.0f * BETA * A[j] * T;
            d[j] = eta[j] + 2.0f * ALPHA * x[j] * x[j];
        }

        // --- tier-1 gate: |det| > rowmax^4 / 1024  =>  kappa <= 1024 ---
        float mind = fminf(fminf(fabsf(d[0]), fabsf(d[1])),
                           fminf(fabsf(d[2]), fabsf(d[3])));
        float p01 = d[0] * d[1], p23 = d[2] * d[3];
        float prod = p01 * p23;
        float det = prod
            + C2 * (A[0]*A[0]*(d[1]*p23) + A[1]*A[1]*(d[0]*p23) +
                    A[2]*A[2]*(p01*d[3]) + A[3]*A[3]*(p01*d[2]));
        float rowmax = 0.0f;
        #pragma unroll
        for (int r = 0; r < 4; ++r) {
            float rs = 0.0f;
            #pragma unroll
            for (int c = 0; c < 4; ++c) {
                float Jrc = C2 * A[r] * A[c] + ((r == c) ? d[r] : 0.0f);
                rs += fabsf(Jrc);
            }
            rowmax = fmaxf(rs, rowmax);
        }
        float sig2 = rowmax * rowmax;
        bool safe = (fabsf(det) > sig2 * sig2 * (1.0f / 1024.0f)) && (mind > 1e-3f);

        if (safe) {
            float invprod = rcp_nr(prod);
            float invd[4] = { d[1] * p23 * invprod, d[0] * p23 * invprod,
                              p01 * d[3] * invprod, p01 * d[2] * invprod };
            float b[4], fd[4], den = 1.0f, w = 0.0f;
            #pragma unroll
            for (int j = 0; j < 4; ++j) {
                b[j]  = A[j] * invd[j];
                fd[j] = f[j] * invd[j];
                den   = fmaf(C2 * A[j], b[j], den);
                w     = fmaf(b[j], f[j], w);
            }
            float scale = (C2 * w) * rcp_nr(den);
            float4 res;
            res.x = fd[0] - b[0] * scale; res.y = fd[1] - b[1] * scale;
            res.z = fd[2] - b[2] * scale; res.w = fd[3] - b[3] * scale;
            ((float4*)out)[i] = res;
        } else {
            int k = atomicAdd(&sCount, 1);     // LDS atomic, cheap
            sList[k] = i;
        }
    }
    __syncthreads();

    // --- in-block mop-up: f64 model + criterion + SM only (no Jacobi) ---
    int nd = sCount;
    if ((int)threadIdx.x < nd) {
        int ii = sList[threadIdx.x];
        float4 xv = y4[2 * ii];
        float4 uv = y4[2 * ii + 1];
        double x[4] = {xv.x, xv.y, xv.z, xv.w};
        double u[4] = {uv.x, uv.y, uv.z, uv.w};
        double A[4], f[4], d[4];
        model_terms_f64(sWd, sVd, x, u, A, f, d);

        bool safe64 = criterion_f64(d, A);
        bool deferred = false;
        if (!safe64) {
            unsigned int idx = atomicAdd(cnt, 1u);   // ~2 per block, cheap
            if (idx < cap) { list[idx] = ii; deferred = true; }
        }
        if (!deferred) {
            double acc[4];
            sm_solve_f64(d, A, f, acc);   // safe64, or ws-overflow fallback
            float4 res;
            res.x = (float)acc[0]; res.y = (float)acc[1];
            res.z = (float)acc[2]; res.w = (float)acc[3];
            ((float4*)out)[ii] = res;
        }
    }
}

// ------- Slow kernel: register-resident Jacobi pinv on global list --------
__global__ __launch_bounds__(64, 1) void slow_kernel(
    const float* __restrict__ y, const float* __restrict__ W,
    const float* __restrict__ V, float* __restrict__ out,
    const unsigned int* __restrict__ cnt, const int* __restrict__ list,
    unsigned int cap)
{
    __shared__ double sW[16], sV[16];
    if (threadIdx.x < 16)      sW[threadIdx.x]      = (double)W[threadIdx.x];
    else if (threadIdx.x < 32) sV[threadIdx.x - 16] = (double)V[threadIdx.x - 16];
    __syncthreads();

    unsigned int n = *cnt;
    if (n > cap) n = cap;
    int stride = gridDim.x * blockDim.x;
    for (unsigned int j = blockIdx.x * blockDim.x + threadIdx.x; j < n; j += stride) {
        int i = list[j];
        const float4* y4 = (const float4*)y;
        float4 xv = y4[2 * i];
        float4 uv = y4[2 * i + 1];
        double x[4] = {xv.x, xv.y, xv.z, xv.w};
        double u[4] = {uv.x, uv.y, uv.z, uv.w};
        double A[4], f[4], d[4];
        model_terms_f64(sW, sV, x, u, A, f, d);

        double acc[4];
        jacobi_pinv_reg(d, A, f, acc);

        float4 res;
        res.x = (float)acc[0]; res.y = (float)acc[1];
        res.z = (float)acc[2]; res.w = (float)acc[3];
        ((float4*)out)[i] = res;
    }
}

extern "C" void kernel_launch(void* const* d_in, const int* in_sizes, int n_in,
                              void* d_out, int out_size, void* d_ws, size_t ws_size,
                              hipStream_t stream) {
    const float* y = (const float*)d_in[0];
    const float* W = (const float*)d_in[1];
    const float* V = (const float*)d_in[2];
    float* out = (float*)d_out;
    int B = in_sizes[0] / 8;

    unsigned int* cnt = (unsigned int*)d_ws;
    int* list = (int*)((char*)d_ws + 16);
    unsigned int cap = (ws_size > 16) ? (unsigned int)((ws_size - 16) / sizeof(int)) : 0u;
    if (cap > (unsigned int)B) cap = (unsigned int)B;

    hipMemsetAsync(d_ws, 0, 16, stream);   // zero the counter (capture-legal)

    int block = 256;
    int grid = (B + block - 1) / block;
    fused_kernel<<<grid, block, 0, stream>>>(y, W, V, out, cnt, list, cap, B);
    slow_kernel<<<128, 64, 0, stream>>>(y, W, V, out, cnt, list, cap);
}

// Round 9
// 78.648 us; speedup vs baseline: 1.2156x; 1.0894x over previous
//
#include <hip/hip_runtime.h>
#include <math.h>

// Constants: MASS=1.0, CHARGE=0.5, ALPHA=0.1, BETA=0.05, ETA=(+1,-1,-1,-1)
// Round 15: R8 structure + stashed-model slow path.
//   - fused_kernel: tier-1 f32 SM (kappa<=1024 gate) + per-block LDS
//     compaction; mop-up runs f64 model + SIX_RCOND criterion + f64 SM.
//     Truly-unsafe lanes stash their f64 model outputs (A,f,d = 12 doubles)
//     + index into the workspace, so the Jacobi kernel needs no model.
//   - slow_kernel: PURE register-resident Jacobi + truncated pinv (rcond =
//     10*max(M,N)*eps_f32 = jnp.linalg.pinv default) on the stashed data.
//     64-thread blocks, __launch_bounds__(64,1) -> ~512-VGPR budget; with
//     the model removed the live set is ~100 VGPR -> no spill possible.
//   - Jacobi sweeps 8 -> 6 (4x4 cyclic Jacobi converges to ~1e-20 off-diag
//     by sweep 5; eigenvalue error << the 5e-6*sigma truncation scale).
// Routing semantics identical to R4/R6/R8 (same gates, same lanes).

#define SIX_RCOND 2.86102294921875e-5   // 6 * 4.76837158203125e-6
#define RCOND     4.76837158203125e-6

// ------------------------------ f32 helpers --------------------------------
__device__ __forceinline__ float rcp_nr(float x) {
    float r = __builtin_amdgcn_rcpf(x);
    r = r * (2.0f - x * r);              // one Newton step -> ~1 ulp
    return r;
}

// ------------------------------ f64 helpers --------------------------------
__device__ __forceinline__ void fast_tanh4(const double t[4], double th[4])
{
    const double LOG2E = 1.4426950408889634074;
    const double LN2HI = 6.93147180369123816490e-01;
    const double LN2LO = 1.90821492927058770002e-10;
    double e[4], opp[4];
    #pragma unroll
    for (int j = 0; j < 4; ++j) {
        double a  = fabs(t[j]);
        double z  = -2.0 * a;
        double zc = fmax(z, -64.0);
        double nf = rint(zc * LOG2E);
        double r  = fma(-nf, LN2HI, zc);
        r = fma(-nf, LN2LO, r);
        double p = 2.75573192239858906526e-07;
        p = fma(p, r, 2.75573192239858925110e-06);
        p = fma(p, r, 2.48015873015873015873e-05);
        p = fma(p, r, 1.98412698412698412698e-04);
        p = fma(p, r, 1.38888888888888888889e-03);
        p = fma(p, r, 8.33333333333333333333e-03);
        p = fma(p, r, 4.16666666666666666667e-02);
        p = fma(p, r, 1.66666666666666666667e-01);
        p = fma(p, r, 0.5);
        p = fma(p, r, 1.0);
        p = fma(p, r, 1.0);
        int n = (int)nf;
        double twon = __longlong_as_double(((long long)(1023 + n)) << 52);
        double ez = p * twon;
        ez = (z <= -40.0) ? 0.0 : ez;
        e[j]   = ez;
        opp[j] = 1.0 + ez;
    }
    double p01 = opp[0] * opp[1], p23 = opp[2] * opp[3];
    double rp  = 1.0 / (p01 * p23);
    double inv[4] = { opp[1] * p23 * rp, opp[0] * p23 * rp,
                      p01 * opp[3] * rp, p01 * opp[2] * rp };
    #pragma unroll
    for (int j = 0; j < 4; ++j)
        th[j] = copysign((1.0 - e[j]) * inv[j], t[j]);
}

__device__ __forceinline__ void model_terms_f64(
    const double* sW, const double* sV,
    const double x[4], const double u[4],
    double A[4], double f[4], double d[4])
{
    const double eta[4] = {1.0, -1.0, -1.0, -1.0};
    const double CHG = 0.5, ALPHA = 0.1, BETA = 0.05;
    double t[4], s[4];
    #pragma unroll
    for (int j = 0; j < 4; ++j) {
        double tj = 0.0, sj = 0.0;
        #pragma unroll
        for (int k = 0; k < 4; ++k) {
            tj = fma(sW[j*4+k], x[k], tj);
            sj = fma(sV[j*4+k], x[k], sj);
        }
        t[j] = tj; s[j] = sj;
    }
    double th[4];
    fast_tanh4(t, th);
    double G[4][4];
    #pragma unroll
    for (int j = 0; j < 4; ++j) {
        A[j] = th[j] + s[j];
        double dth = 1.0 - th[j] * th[j];
        #pragma unroll
        for (int k = 0; k < 4; ++k) G[j][k] = fma(dth, sW[j*4+k], sV[j*4+k]);
    }
    double S = 0.0;
    #pragma unroll
    for (int k = 0; k < 4; ++k) S += u[k] * A[k];
    double P[4], R[4], Q[4];
    #pragma unroll
    for (int j = 0; j < 4; ++j) {
        double p = 0.0, r = 0.0, q = 0.0;
        #pragma unroll
        for (int k = 0; k < 4; ++k) {
            p += G[k][j] * u[k];
            r += G[j][k] * u[k];
            q += G[k][j] * (CHG * eta[k]) * u[k];
        }
        P[j] = p; R[j] = r; Q[j] = q;
    }
    double T = 0.0;
    #pragma unroll
    for (int j = 0; j < 4; ++j) T += u[j] * R[j];
    #pragma unroll
    for (int j = 0; j < 4; ++j) {
        f[j] = -2.0 * ALPHA * x[j] * u[j] * u[j]
             + Q[j]
             + 2.0 * BETA * S * P[j]
             - (CHG * eta[j] + 2.0 * BETA * S) * R[j]
             - 2.0 * BETA * A[j] * T;
        d[j] = eta[j] + 2.0 * ALPHA * x[j] * x[j];
    }
}

__device__ __forceinline__ void sm_solve_f64(
    const double d[4], const double A[4], const double f[4], double acc[4])
{
    const double C2 = 0.1;
    double b[4], fd[4], den = 1.0, w = 0.0;
    #pragma unroll
    for (int j = 0; j < 4; ++j) {
        double inv = 1.0 / d[j];
        b[j]  = A[j] * inv;
        fd[j] = f[j] * inv;
        den  += C2 * A[j] * b[j];
        w    += b[j] * f[j];
    }
    double scale = C2 * w / den;
    #pragma unroll
    for (int j = 0; j < 4; ++j) acc[j] = fd[j] - b[j] * scale;
}

// f64 safety criterion: |det| > SIX_RCOND * min(F2, rowmax^2)^2 && min|d|>1e-3
__device__ __forceinline__ bool criterion_f64(
    const double d[4], const double A[4])
{
    const double C2 = 0.1;
    double mind = 1e300;
    #pragma unroll
    for (int j = 0; j < 4; ++j) {
        double a = fabs(d[j]);
        mind = (a < mind) ? a : mind;
    }
    double p01 = d[0] * d[1], p23 = d[2] * d[3];
    double det = p01 * p23
        + C2 * (A[0]*A[0]*(d[1]*p23) + A[1]*A[1]*(d[0]*p23) +
                A[2]*A[2]*(p01*d[3]) + A[3]*A[3]*(p01*d[2]));
    double sumA2 = 0.0, sumA4 = 0.0, F2 = 0.0;
    #pragma unroll
    for (int j = 0; j < 4; ++j) {
        double Aj2 = A[j] * A[j];
        sumA2 += Aj2; sumA4 += Aj2 * Aj2;
        double Jjj = d[j] + C2 * Aj2;
        F2 += Jjj * Jjj;
    }
    F2 += C2 * C2 * (sumA2 * sumA2 - sumA4);
    double rowmax = 0.0;
    #pragma unroll
    for (int r = 0; r < 4; ++r) {
        double rs = 0.0;
        #pragma unroll
        for (int c = 0; c < 4; ++c) {
            double Jrc = C2 * A[r] * A[c] + ((r == c) ? d[r] : 0.0);
            rs += fabs(Jrc);
        }
        rowmax = (rs > rowmax) ? rs : rowmax;
    }
    double sig_hi2 = rowmax * rowmax;
    sig_hi2 = (F2 < sig_hi2) ? F2 : sig_hi2;
    return (fabs(det) > SIX_RCOND * sig_hi2 * sig_hi2) && (mind > 1e-3);
}

// Branch-free 4x4 symmetric Jacobi + truncated pinv, register-resident.
__device__ __forceinline__ void jacobi_pinv_reg(
    const double d[4], const double A[4], const double f[4], double acc[4])
{
    const double C2 = 0.1;
    double M[4][4], Vm[4][4];
    #pragma unroll
    for (int r = 0; r < 4; ++r) {
        #pragma unroll
        for (int c = 0; c < 4; ++c) {
            M[r][c] = C2 * A[r] * A[c];
            Vm[r][c] = (r == c) ? 1.0 : 0.0;
        }
        M[r][r] += d[r];
    }
    for (int sweep = 0; sweep < 6; ++sweep) {
        #pragma unroll
        for (int p = 0; p < 3; ++p) {
            #pragma unroll
            for (int q2 = p + 1; q2 < 4; ++q2) {
                double apq = M[p][q2];
                bool active = fabs(apq) > 1e-280;
                double div = active ? (2.0 * apq) : 1.0;
                double tau = (M[q2][q2] - M[p][p]) / div;
                double tt = ((tau >= 0.0) ? 1.0 : -1.0) /
                            (fabs(tau) + sqrt(1.0 + tau * tau));
                double c = 1.0 / sqrt(1.0 + tt * tt);
                double s = tt * c;
                c = active ? c : 1.0;     // identity rotation if apq ~ 0
                s = active ? s : 0.0;
                #pragma unroll
                for (int k = 0; k < 4; ++k) {
                    double mkp = M[k][p], mkq = M[k][q2];
                    M[k][p]  = c * mkp - s * mkq;
                    M[k][q2] = s * mkp + c * mkq;
                }
                #pragma unroll
                for (int k = 0; k < 4; ++k) {
                    double mpk = M[p][k], mqk = M[q2][k];
                    M[p][k]  = c * mpk - s * mqk;
                    M[q2][k] = s * mpk + c * mqk;
                }
                #pragma unroll
                for (int k = 0; k < 4; ++k) {
                    double vkp = Vm[k][p], vkq = Vm[k][q2];
                    Vm[k][p]  = c * vkp - s * vkq;
                    Vm[k][q2] = s * vkp + c * vkq;
                }
            }
        }
    }
    double lam[4], sigmax = 0.0;
    #pragma unroll
    for (int k = 0; k < 4; ++k) {
        lam[k] = M[k][k];
        double a = fabs(lam[k]);
        sigmax = (a > sigmax) ? a : sigmax;
    }
    double cutoff = RCOND * sigmax;
    #pragma unroll
    for (int j = 0; j < 4; ++j) acc[j] = 0.0;
    #pragma unroll
    for (int e = 0; e < 4; ++e) {
        double coef = 0.0;
        #pragma unroll
        for (int k = 0; k < 4; ++k) coef += Vm[k][e] * f[k];
        coef /= lam[e];
        coef = (fabs(lam[e]) > cutoff) ? coef : 0.0;   // truncate small modes
        #pragma unroll
        for (int j = 0; j < 4; ++j) acc[j] += coef * Vm[j][e];
    }
}

// ------- Fused kernel: f32 tier-1 + in-block f64 model/SM mop-up -----------
// Truly-unsafe lanes stash (A,f,d,idx) so slow_kernel is model-free.
__global__ __launch_bounds__(256, 2) void fused_kernel(
    const float* __restrict__ y, const float* __restrict__ W,
    const float* __restrict__ V, float* __restrict__ out,
    unsigned int* __restrict__ cnt, double* __restrict__ data,
    int* __restrict__ idxs, unsigned int cap, int B)
{
    __shared__ float  sW[16],  sV[16];
    __shared__ double sWd[16], sVd[16];
    __shared__ int sList[256];
    __shared__ int sCount;

    if (threadIdx.x == 0) sCount = 0;
    if (threadIdx.x < 16) {
        float w = W[threadIdx.x];
        sW[threadIdx.x]  = w;
        sWd[threadIdx.x] = (double)w;
    } else if (threadIdx.x < 32) {
        float v = V[threadIdx.x - 16];
        sV[threadIdx.x - 16]  = v;
        sVd[threadIdx.x - 16] = (double)v;
    }
    __syncthreads();

    int i = blockIdx.x * blockDim.x + threadIdx.x;
    const float4* y4 = (const float4*)y;

    if (i < B) {
        float4 xv = y4[2 * i];
        float4 uv = y4[2 * i + 1];
        float x[4] = {xv.x, xv.y, xv.z, xv.w};
        float u[4] = {uv.x, uv.y, uv.z, uv.w};

        const float eta[4] = {1.0f, -1.0f, -1.0f, -1.0f};
        const float CHG = 0.5f, ALPHA = 0.1f, BETA = 0.05f, C2 = 0.1f;
        const float NEG2LOG2E = -2.8853900817779268f;   // -2*log2(e)

        float t[4], sv[4];
        #pragma unroll
        for (int j = 0; j < 4; ++j) {
            float tj = 0.0f, sj = 0.0f;
            #pragma unroll
            for (int k = 0; k < 4; ++k) {
                tj = fmaf(sW[j*4+k], x[k], tj);
                sj = fmaf(sV[j*4+k], x[k], sj);
            }
            t[j] = tj; sv[j] = sj;
        }
        float A[4], dth[4];
        #pragma unroll
        for (int j = 0; j < 4; ++j) {
            float a  = fabsf(t[j]);
            float e  = __builtin_amdgcn_exp2f(a * NEG2LOG2E); // underflow->0 -> th=1
            float th = copysignf((1.0f - e) * rcp_nr(1.0f + e), t[j]);
            A[j]   = th + sv[j];
            dth[j] = 1.0f - th * th;
        }
        float G[4][4];
        #pragma unroll
        for (int j = 0; j < 4; ++j)
            #pragma unroll
            for (int k = 0; k < 4; ++k)
                G[j][k] = fmaf(dth[j], sW[j*4+k], sV[j*4+k]);

        float S = 0.0f;
        #pragma unroll
        for (int k = 0; k < 4; ++k) S = fmaf(u[k], A[k], S);
        float P[4], R[4], Q[4];
        #pragma unroll
        for (int j = 0; j < 4; ++j) {
            float p = 0.0f, r = 0.0f, q = 0.0f;
            #pragma unroll
            for (int k = 0; k < 4; ++k) {
                p = fmaf(G[k][j], u[k], p);
                r = fmaf(G[j][k], u[k], r);
                q = fmaf(G[k][j] * (CHG * eta[k]), u[k], q);
            }
            P[j] = p; R[j] = r; Q[j] = q;
        }
        float T = 0.0f;
        #pragma unroll
        for (int j = 0; j < 4; ++j) T = fmaf(u[j], R[j], T);
        float f[4], d[4];
        #pragma unroll
        for (int j = 0; j < 4; ++j) {
            f[j] = -2.0f * ALPHA * x[j] * u[j] * u[j]
                 + Q[j]
                 + 2.0f * BETA * S * P[j]
                 - (CHG * eta[j] + 2.0f * BETA * S) * R[j]
                 - 2.0f * BETA * A[j] * T;
            d[j] = eta[j] + 2.0f * ALPHA * x[j] * x[j];
        }

        // --- tier-1 gate: |det| > rowmax^4 / 1024  =>  kappa <= 1024 ---
        float mind = fminf(fminf(fabsf(d[0]), fabsf(d[1])),
                           fminf(fabsf(d[2]), fabsf(d[3])));
        float p01 = d[0] * d[1], p23 = d[2] * d[3];
        float prod = p01 * p23;
        float det = prod
            + C2 * (A[0]*A[0]*(d[1]*p23) + A[1]*A[1]*(d[0]*p23) +
                    A[2]*A[2]*(p01*d[3]) + A[3]*A[3]*(p01*d[2]));
        float rowmax = 0.0f;
        #pragma unroll
        for (int r = 0; r < 4; ++r) {
            float rs = 0.0f;
            #pragma unroll
            for (int c = 0; c < 4; ++c) {
                float Jrc = C2 * A[r] * A[c] + ((r == c) ? d[r] : 0.0f);
                rs += fabsf(Jrc);
            }
            rowmax = fmaxf(rs, rowmax);
        }
        float sig2 = rowmax * rowmax;
        bool safe = (fabsf(det) > sig2 * sig2 * (1.0f / 1024.0f)) && (mind > 1e-3f);

        if (safe) {
            float invprod = rcp_nr(prod);
            float invd[4] = { d[1] * p23 * invprod, d[0] * p23 * invprod,
                              p01 * d[3] * invprod, p01 * d[2] * invprod };
            float b[4], fd[4], den = 1.0f, w = 0.0f;
            #pragma unroll
            for (int j = 0; j < 4; ++j) {
                b[j]  = A[j] * invd[j];
                fd[j] = f[j] * invd[j];
                den   = fmaf(C2 * A[j], b[j], den);
                w     = fmaf(b[j], f[j], w);
            }
            float scale = (C2 * w) * rcp_nr(den);
            float4 res;
            res.x = fd[0] - b[0] * scale; res.y = fd[1] - b[1] * scale;
            res.z = fd[2] - b[2] * scale; res.w = fd[3] - b[3] * scale;
            ((float4*)out)[i] = res;
        } else {
            int k = atomicAdd(&sCount, 1);     // LDS atomic, cheap
            sList[k] = i;
        }
    }
    __syncthreads();

    // --- in-block mop-up: f64 model + criterion + SM; stash unsafe lanes ---
    int nd = sCount;
    if ((int)threadIdx.x < nd) {
        int ii = sList[threadIdx.x];
        float4 xv = y4[2 * ii];
        float4 uv = y4[2 * ii + 1];
        double x[4] = {xv.x, xv.y, xv.z, xv.w};
        double u[4] = {uv.x, uv.y, uv.z, uv.w};
        double A[4], f[4], d[4];
        model_terms_f64(sWd, sVd, x, u, A, f, d);

        bool safe64 = criterion_f64(d, A);
        bool deferred = false;
        if (!safe64) {
            unsigned int idx = atomicAdd(cnt, 1u);   // ~2 per block, cheap
            if (idx < cap) {
                double* rec = data + (size_t)idx * 12;
                #pragma unroll
                for (int j = 0; j < 4; ++j) rec[j]     = A[j];
                #pragma unroll
                for (int j = 0; j < 4; ++j) rec[4 + j] = f[j];
                #pragma unroll
                for (int j = 0; j < 4; ++j) rec[8 + j] = d[j];
                idxs[idx] = ii;
                deferred = true;
            }
        }
        if (!deferred) {
            double acc[4];
            sm_solve_f64(d, A, f, acc);   // safe64, or ws-overflow fallback
            float4 res;
            res.x = (float)acc[0]; res.y = (float)acc[1];
            res.z = (float)acc[2]; res.w = (float)acc[3];
            ((float4*)out)[ii] = res;
        }
    }
}

// ------- Slow kernel: pure register Jacobi pinv on stashed (A,f,d) --------
__global__ __launch_bounds__(64, 1) void slow_kernel(
    float* __restrict__ out,
    const unsigned int* __restrict__ cnt, const double* __restrict__ data,
    const int* __restrict__ idxs, unsigned int cap)
{
    unsigned int n = *cnt;
    if (n > cap) n = cap;
    int stride = gridDim.x * blockDim.x;
    for (unsigned int j = blockIdx.x * blockDim.x + threadIdx.x; j < n; j += stride) {
        const double* rec = data + (size_t)j * 12;
        double A[4], f[4], d[4];
        #pragma unroll
        for (int k = 0; k < 4; ++k) A[k] = rec[k];
        #pragma unroll
        for (int k = 0; k < 4; ++k) f[k] = rec[4 + k];
        #pragma unroll
        for (int k = 0; k < 4; ++k) d[k] = rec[8 + k];
        int i = idxs[j];

        double acc[4];
        jacobi_pinv_reg(d, A, f, acc);

        float4 res;
        res.x = (float)acc[0]; res.y = (float)acc[1];
        res.z = (float)acc[2]; res.w = (float)acc[3];
        ((float4*)out)[i] = res;
    }
}

extern "C" void kernel_launch(void* const* d_in, const int* in_sizes, int n_in,
                              void* d_out, int out_size, void* d_ws, size_t ws_size,
                              hipStream_t stream) {
    const float* y = (const float*)d_in[0];
    const float* W = (const float*)d_in[1];
    const float* V = (const float*)d_in[2];
    float* out = (float*)d_out;
    int B = in_sizes[0] / 8;

    // ws layout: [0..16) cnt; [16 .. 16+cap*96) stashed records (12 doubles);
    // [16+cap*96 .. ) int index list.
    unsigned int* cnt = (unsigned int*)d_ws;
    unsigned int cap = 0;
    if (ws_size > 16) {
        size_t avail = ws_size - 16;
        cap = (unsigned int)(avail / (12 * sizeof(double) + sizeof(int)));
    }
    if (cap > (unsigned int)B) cap = (unsigned int)B;
    double* data = (double*)((char*)d_ws + 16);
    int* idxs = (int*)((char*)d_ws + 16 + (size_t)cap * 12 * sizeof(double));

    hipMemsetAsync(d_ws, 0, 16, stream);   // zero the counter (capture-legal)

    int block = 256;
    int grid = (B + block - 1) / block;
    fused_kernel<<<grid, block, 0, stream>>>(y, W, V, out, cnt, data, idxs, cap, B);
    slow_kernel<<<128, 64, 0, stream>>>(out, cnt, data, idxs, cap);
}